// Round 4
// baseline (11290.139 us; speedup 1.0000x reference)
//
#include <hip/hip_runtime.h>
#include <math.h>

#define NA 10
#define NT 65
#define NB 128
#define XDIM 2
#define YDIM 20
#define ZDIM 64
#define HDIM 256
#define RMDIM 256
#define NSTEP 64
#define TS 8
#define HR (TS + 1)
#define LOG2PI 1.8378770664093453f

#define ENC_W1_S (348 * 256)
#define PRI_W1_S (346 * 256)
#define DEC_W1_S (430 * 256)
#define GRU_WIH_S (66 * 768)
#define GRU_WHH_S (256 * 768)
#define W2_S (256 * 256)
#define HEADW_S (256 * 64)

// column-major activation panels: [C][NB] per agent
#define SA (256 * NB)   // 256-col panel per agent
#define GA (768 * NB)   // 768-col panel per agent
#define ZA (ZDIM * NB)  // 64-col panel per agent

static __device__ __forceinline__ float sp(float x) {
    return fmaxf(x, 0.f) + log1pf(expf(-fabsf(x)));
}
static __device__ __forceinline__ float sigm(float x) { return 1.f / (1.f + expf(-x)); }
static __device__ __forceinline__ float relu(float x) { return fmaxf(x, 0.f); }

__global__ __launch_bounds__(256) void k_init(float* __restrict__ h0, double* __restrict__ accd) {
    int i = blockIdx.x * 256 + threadIdx.x;
    ((float4*)h0)[i] = make_float4(0.f, 0.f, 0.f, 0.f);  // grid 320 -> NA*SA floats
    if (i == 0) {
        accd[0] = 0.0;
        accd[1] = 0.0;
    }
}

// ---- S1: enc1 (tiles 0..7), pri1 (8..15), gh (16..39). K=256 over h_t (col-major). grid 800.
__global__ __launch_bounds__(256) void kS1(const float* __restrict__ h,
                                           const float* __restrict__ enc_W1,
                                           const float* __restrict__ enc_b1,
                                           const float* __restrict__ pri_W1,
                                           const float* __restrict__ pri_b1,
                                           const float* __restrict__ gru_Whh,
                                           const float* __restrict__ gru_bhh,
                                           const float* __restrict__ data,
                                           const int* __restrict__ macro, float* __restrict__ ench1,
                                           float* __restrict__ prih1, float* __restrict__ ghB,
                                           int t) {
    int tid = threadIdx.x, bid = blockIdx.x;
    int lane = tid & 63, wv = tid >> 6;
    int a = bid / 80;
    int r = bid % 80;
    int b0 = (r & 1) * 64;
    int tile = r >> 1;
    int ep, c0;
    const float* Wb;
    int wld;
    if (tile < 8) {
        ep = 0; c0 = tile * 32;
        Wb = enc_W1 + a * ENC_W1_S + 92 * 256; wld = 256;
    } else if (tile < 16) {
        ep = 1; c0 = (tile - 8) * 32;
        Wb = pri_W1 + a * PRI_W1_S + 90 * 256; wld = 256;
    } else {
        ep = 2; c0 = (tile - 16) * 32;
        Wb = gru_Whh + a * GRU_WHH_S; wld = 768;
    }
    int n0u = __builtin_amdgcn_readfirstlane(c0 + wv * 8);
    int row = b0 + lane;
    const float* X = h + a * SA + row;
    const float* wp = Wb + n0u;
    float acc[8] = {};
#pragma unroll 8
    for (int k = 0; k < 256; ++k) {
        float xv = X[k * NB];
        const float* wr = wp + k * wld;
#pragma unroll
        for (int j = 0; j < 8; ++j) acc[j] = fmaf(xv, wr[j], acc[j]);
    }
    if (ep == 2) {
#pragma unroll
        for (int j = 0; j < 8; ++j) {
            float v = acc[j] + gru_bhh[a * 768 + n0u + j];
            ghB[a * GA + (n0u + j) * NB + row] = v;
        }
    } else {
        const float* W1b = (ep == 0) ? enc_W1 + a * ENC_W1_S : pri_W1 + a * PRI_W1_S;
        const float* bb = (ep == 0) ? enc_b1 + a * HDIM : pri_b1 + a * HDIM;
        int mi = macro[(t * NB + row) * NA + a];
        const float* mrow = W1b + (ep == 0 ? 2 + mi : mi) * 256;
        float xv0 = 0.f, xv1 = 0.f;
        if (ep == 0) {
            xv0 = data[(t + 1) * (NB * YDIM) + row * YDIM + a * XDIM];
            xv1 = data[(t + 1) * (NB * YDIM) + row * YDIM + a * XDIM + 1];
        }
        float* outp = (ep == 0) ? ench1 : prih1;
#pragma unroll
        for (int j = 0; j < 8; ++j) {
            float v = acc[j] + bb[n0u + j] + mrow[n0u + j];
            if (ep == 0) v += xv0 * W1b[n0u + j] + xv1 * W1b[256 + n0u + j];
            outp[a * SA + (n0u + j) * NB + row] = relu(v);
        }
    }
}

// ---- S2: enc2 (r<16), pri2 (r>=16). K=256. grid 320.
__global__ __launch_bounds__(256) void kS2(const float* __restrict__ ench1,
                                           const float* __restrict__ prih1,
                                           const float* __restrict__ enc_W2,
                                           const float* __restrict__ enc_b2,
                                           const float* __restrict__ pri_W2,
                                           const float* __restrict__ pri_b2,
                                           float* __restrict__ ench2, float* __restrict__ prih2) {
    int tid = threadIdx.x, bid = blockIdx.x;
    int lane = tid & 63, wv = tid >> 6;
    int a = bid / 32;
    int r = bid % 32;
    int isenc = (r < 16);
    int q = isenc ? r : r - 16;
    int b0 = (q & 1) * 64;
    int c0 = (q >> 1) * 32;
    int n0u = __builtin_amdgcn_readfirstlane(c0 + wv * 8);
    int row = b0 + lane;
    const float* X = (isenc ? ench1 : prih1) + a * SA + row;
    const float* wp = (isenc ? enc_W2 : pri_W2) + a * W2_S + n0u;
    const float* bb = (isenc ? enc_b2 : pri_b2) + a * HDIM;
    float acc[8] = {};
#pragma unroll 8
    for (int k = 0; k < 256; ++k) {
        float xv = X[k * NB];
        const float* wr = wp + k * 256;
#pragma unroll
        for (int j = 0; j < 8; ++j) acc[j] = fmaf(xv, wr[j], acc[j]);
    }
    float* outp = isenc ? ench2 : prih2;
#pragma unroll
    for (int j = 0; j < 8; ++j)
        outp[a * SA + (n0u + j) * NB + row] = relu(acc[j] + bb[n0u + j]);
}

// ---- S3: 4 z-heads (one head per wave, 16 z-cols per block-tile) + z + KL. grid 80.
__global__ __launch_bounds__(256) void kS3(const float* __restrict__ ench2,
                                           const float* __restrict__ prih2,
                                           const float* __restrict__ encm_W,
                                           const float* __restrict__ encm_b,
                                           const float* __restrict__ encs_W,
                                           const float* __restrict__ encs_b,
                                           const float* __restrict__ prim_W,
                                           const float* __restrict__ prim_b,
                                           const float* __restrict__ pris_W,
                                           const float* __restrict__ pris_b,
                                           const float* __restrict__ eps, float* __restrict__ z_t,
                                           double* __restrict__ accd, int t) {
    __shared__ float L[4][16][64];
    __shared__ float red[256];
    int tid = threadIdx.x, bid = blockIdx.x;
    int lane = tid & 63, wv = tid >> 6;
    int a = bid / 8;
    int r = bid % 8;
    int b0 = (r & 1) * 64;
    int zc0 = (r >> 1) * 16;
    int row = b0 + lane;
    const float* Wt;
    const float* Bt;
    if (wv == 0) { Wt = encm_W; Bt = encm_b; }
    else if (wv == 1) { Wt = encs_W; Bt = encs_b; }
    else if (wv == 2) { Wt = prim_W; Bt = prim_b; }
    else { Wt = pris_W; Bt = pris_b; }
    const float* X = (wv < 2 ? ench2 : prih2) + a * SA + row;
    const float* wp = Wt + a * HEADW_S + zc0;
    float acc[16] = {};
#pragma unroll 4
    for (int k = 0; k < 256; ++k) {
        float xv = X[k * NB];
        const float* wr = wp + k * ZDIM;
#pragma unroll
        for (int j = 0; j < 16; ++j) acc[j] = fmaf(xv, wr[j], acc[j]);
    }
#pragma unroll
    for (int j = 0; j < 16; ++j) L[wv][j][lane] = acc[j] + Bt[a * ZDIM + zc0 + j];
    __syncthreads();
    // each thread: 4 z-cols (wv*4 .. wv*4+3) for its row
    float part = 0.f;
#pragma unroll
    for (int q = 0; q < 4; ++q) {
        int zc = wv * 4 + q;
        float em = L[0][zc][lane];
        float es = sp(L[1][zc][lane]);
        float pm = L[2][zc][lane];
        float ps = sp(L[3][zc][lane]);
        float ev = eps[((t * NA + a) * NB + row) * ZDIM + zc0 + zc];
        z_t[a * ZA + (zc0 + zc) * NB + row] = em + ev * es;
        float dm = em - pm;
        part += 0.5f * (2.f * logf(ps) - 2.f * logf(es) + (es * es + dm * dm) / (ps * ps) - 1.f);
    }
    red[tid] = part;
    __syncthreads();
#pragma unroll
    for (int s = 128; s > 0; s >>= 1) {
        if (tid < s) red[tid] += red[tid + s];
        __syncthreads();
    }
    if (tid == 0) atomicAdd(&accd[1], (double)red[0]);
}

// ---- S4: gi (3 gates, K=64 over z) + GRU combine -> h_{t+1}. grid 160.
__global__ __launch_bounds__(256) void kS4(const float* __restrict__ z_t,
                                           const float* __restrict__ data,
                                           const float* __restrict__ gru_Wih,
                                           const float* __restrict__ gru_bih,
                                           const float* __restrict__ ghB,
                                           const float* __restrict__ h_t, float* __restrict__ h_nx,
                                           int t) {
    int tid = threadIdx.x, bid = blockIdx.x;
    int lane = tid & 63, wv = tid >> 6;
    int a = bid / 16;
    int r = bid % 16;
    int b0 = (r & 1) * 64;
    int c0 = (r >> 1) * 32;
    int n0u = __builtin_amdgcn_readfirstlane(c0 + wv * 8);
    int row = b0 + lane;
    const float* X = z_t + a * ZA + row;
    const float* wp = gru_Wih + a * GRU_WIH_S + 2 * 768 + n0u;
    float acc[3][8] = {};
#pragma unroll 8
    for (int k = 0; k < 64; ++k) {
        float xv = X[k * NB];
        const float* wr = wp + k * 768;
#pragma unroll
        for (int j = 0; j < 8; ++j) acc[0][j] = fmaf(xv, wr[j], acc[0][j]);
#pragma unroll
        for (int j = 0; j < 8; ++j) acc[1][j] = fmaf(xv, wr[256 + j], acc[1][j]);
#pragma unroll
        for (int j = 0; j < 8; ++j) acc[2][j] = fmaf(xv, wr[512 + j], acc[2][j]);
    }
    float xv0 = data[(t + 1) * (NB * YDIM) + row * YDIM + a * XDIM];
    float xv1 = data[(t + 1) * (NB * YDIM) + row * YDIM + a * XDIM + 1];
    const float* Wih0 = gru_Wih + a * GRU_WIH_S;
    const float* bih = gru_bih + a * 768;
    const float* ghb = ghB + a * GA + row;
    const float* hb = h_t + a * SA + row;
    float* ob = h_nx + a * SA + row;
#pragma unroll
    for (int j = 0; j < 8; ++j) {
        int cr = n0u + j;
        float gi0 = acc[0][j] + bih[cr] + xv0 * Wih0[cr] + xv1 * Wih0[768 + cr];
        float gi1 = acc[1][j] + bih[256 + cr] + xv0 * Wih0[256 + cr] + xv1 * Wih0[768 + 256 + cr];
        float gi2 = acc[2][j] + bih[512 + cr] + xv0 * Wih0[512 + cr] + xv1 * Wih0[768 + 512 + cr];
        float hrv = ghb[cr * NB];
        float hzv = ghb[(256 + cr) * NB];
        float hnv = ghb[(512 + cr) * NB];
        float hov = hb[cr * NB];
        float rr = sigm(gi0 + hrv);
        float uu = sigm(gi1 + hzv);
        float nn = tanhf(gi2 + rr * hnv);
        ob[cr * NB] = (1.f - uu) * nn + uu * hov;
    }
}

// ---- dec1 for TS steps. grid TS*160. K segments: y(20 gather), z(64), h(256); macro in epilogue.
__global__ __launch_bounds__(256) void kDec1(const float* __restrict__ data,
                                             const int* __restrict__ macro,
                                             const float* __restrict__ z_ring,
                                             const float* __restrict__ h_ring,
                                             const float* __restrict__ dec_W1,
                                             const float* __restrict__ dec_b1,
                                             float* __restrict__ dech1s, int t0) {
    int tid = threadIdx.x, bid = blockIdx.x;
    int lane = tid & 63, wv = tid >> 6;
    int ti = bid / 160;
    int rem = bid % 160;
    int a = rem / 16;
    int r = rem % 16;
    int b0 = (r & 1) * 64;
    int c0 = (r >> 1) * 32;
    int t = t0 + ti;
    int n0u = __builtin_amdgcn_readfirstlane(c0 + wv * 8);
    int row = b0 + lane;
    const float* Wb = dec_W1 + a * DEC_W1_S;
    const float* wp = Wb + n0u;
    float acc[8] = {};
    // y segment (k = 0..19), per-lane gather from row-major data
    const float* yrow = data + t * (NB * YDIM) + row * YDIM;
#pragma unroll 4
    for (int k = 0; k < YDIM; ++k) {
        float xv = yrow[k];
        const float* wr = wp + k * 256;
#pragma unroll
        for (int j = 0; j < 8; ++j) acc[j] = fmaf(xv, wr[j], acc[j]);
    }
    // z segment (weight rows 110..173)
    const float* Xz = z_ring + (size_t)(t % TS) * (NA * ZA) + a * ZA + row;
#pragma unroll 8
    for (int k = 0; k < ZDIM; ++k) {
        float xv = Xz[k * NB];
        const float* wr = wp + (110 + k) * 256;
#pragma unroll
        for (int j = 0; j < 8; ++j) acc[j] = fmaf(xv, wr[j], acc[j]);
    }
    // h segment (weight rows 174..429)
    const float* Xh = h_ring + (size_t)(t % HR) * (NA * SA) + a * SA + row;
#pragma unroll 8
    for (int k = 0; k < 256; ++k) {
        float xv = Xh[k * NB];
        const float* wr = wp + (174 + k) * 256;
#pragma unroll
        for (int j = 0; j < 8; ++j) acc[j] = fmaf(xv, wr[j], acc[j]);
    }
    int mi = macro[(t * NB + row) * NA + a];
    const float* mrow = Wb + (20 + mi) * 256;
    const float* bb = dec_b1 + a * HDIM;
    float* ob = dech1s + (size_t)(ti * NA + a) * SA + row;
#pragma unroll
    for (int j = 0; j < 8; ++j)
        ob[(n0u + j) * NB] = relu(acc[j] + bb[n0u + j] + mrow[n0u + j]);
}

__global__ __launch_bounds__(256) void kDec2(const float* __restrict__ dech1s,
                                             const float* __restrict__ dec_W2,
                                             const float* __restrict__ dec_b2,
                                             float* __restrict__ dech2s) {
    int tid = threadIdx.x, bid = blockIdx.x;
    int lane = tid & 63, wv = tid >> 6;
    int ti = bid / 160;
    int rem = bid % 160;
    int a = rem / 16;
    int r = rem % 16;
    int b0 = (r & 1) * 64;
    int c0 = (r >> 1) * 32;
    int n0u = __builtin_amdgcn_readfirstlane(c0 + wv * 8);
    int row = b0 + lane;
    const float* X = dech1s + (size_t)(ti * NA + a) * SA + row;
    const float* wp = dec_W2 + a * W2_S + n0u;
    const float* bb = dec_b2 + a * HDIM;
    float acc[8] = {};
#pragma unroll 8
    for (int k = 0; k < 256; ++k) {
        float xv = X[k * NB];
        const float* wr = wp + k * 256;
#pragma unroll
        for (int j = 0; j < 8; ++j) acc[j] = fmaf(xv, wr[j], acc[j]);
    }
    float* ob = dech2s + (size_t)(ti * NA + a) * SA + row;
#pragma unroll
    for (int j = 0; j < 8; ++j)
        ob[(n0u + j) * NB] = relu(acc[j] + bb[n0u + j]);
}

// dec heads + recon for TS steps: one wave per (ti,a,b). grid TS*320.
__global__ __launch_bounds__(256) void kEpi(const float* __restrict__ dech2s,
                                            const float* __restrict__ decm_W,
                                            const float* __restrict__ decm_b,
                                            const float* __restrict__ decs_W,
                                            const float* __restrict__ decs_b,
                                            const float* __restrict__ data,
                                            double* __restrict__ accd, int t0) {
    int tid = threadIdx.x;
    int widx = blockIdx.x * 4 + (tid >> 6);
    int lane = tid & 63;
    int ti = widx / 1280;
    int rem = widx - ti * 1280;
    int a = rem >> 7, b = rem & 127;
    int targ = t0 + ti + 1;
    const float* dbase = dech2s + (size_t)(ti * NA + a) * SA + b;
    float hv0 = dbase[(lane * 4 + 0) * NB];
    float hv1 = dbase[(lane * 4 + 1) * NB];
    float hv2 = dbase[(lane * 4 + 2) * NB];
    float hv3 = dbase[(lane * 4 + 3) * NB];
    const float* wmb = decm_W + a * (HDIM * XDIM) + lane * 8;
    const float4 wm0 = *(const float4*)&wmb[0];
    const float4 wm1 = *(const float4*)&wmb[4];
    const float* wsb = decs_W + a * (HDIM * XDIM) + lane * 8;
    const float4 ws0 = *(const float4*)&wsb[0];
    const float4 ws1 = *(const float4*)&wsb[4];
    float m0 = hv0 * wm0.x + hv1 * wm0.z + hv2 * wm1.x + hv3 * wm1.z;
    float m1 = hv0 * wm0.y + hv1 * wm0.w + hv2 * wm1.y + hv3 * wm1.w;
    float s0 = hv0 * ws0.x + hv1 * ws0.z + hv2 * ws1.x + hv3 * ws1.z;
    float s1 = hv0 * ws0.y + hv1 * ws0.w + hv2 * ws1.y + hv3 * ws1.w;
#pragma unroll
    for (int off = 32; off > 0; off >>= 1) {
        m0 += __shfl_down(m0, off, 64);
        m1 += __shfl_down(m1, off, 64);
        s0 += __shfl_down(s0, off, 64);
        s1 += __shfl_down(s1, off, 64);
    }
    if (lane == 0) {
        float dm0 = m0 + decm_b[a * 2 + 0];
        float dm1 = m1 + decm_b[a * 2 + 1];
        float ds0 = sp(s0 + decs_b[a * 2 + 0]);
        float ds1 = sp(s1 + decs_b[a * 2 + 1]);
        float x0 = data[targ * (NB * YDIM) + b * YDIM + a * XDIM + 0];
        float x1 = data[targ * (NB * YDIM) + b * YDIM + a * XDIM + 1];
        float r0 = (x0 - dm0) / ds0, r1 = (x1 - dm1) / ds1;
        float tt = 0.5f * r0 * r0 + logf(ds0) + 0.5f * LOG2PI + 0.5f * r1 * r1 + logf(ds1) +
                   0.5f * LOG2PI;
        atomicAdd(&accd[0], (double)tt);
    }
}

__global__ void k_final(const double* __restrict__ accd, float* __restrict__ out) {
    if (threadIdx.x == 0) {
        out[0] = (float)accd[0];
        out[1] = (float)accd[1];
    }
}

extern "C" void kernel_launch(void* const* d_in, const int* in_sizes, int n_in, void* d_out,
                              int out_size, void* d_ws, size_t ws_size, hipStream_t stream) {
    const float* data = (const float*)d_in[0];
    const int* macro = (const int*)d_in[1];
    const float* eps = (const float*)d_in[2];
    const float* enc_W1 = (const float*)d_in[3];
    const float* enc_b1 = (const float*)d_in[4];
    const float* enc_W2 = (const float*)d_in[5];
    const float* enc_b2 = (const float*)d_in[6];
    const float* encm_W = (const float*)d_in[7];
    const float* encm_b = (const float*)d_in[8];
    const float* encs_W = (const float*)d_in[9];
    const float* encs_b = (const float*)d_in[10];
    const float* pri_W1 = (const float*)d_in[11];
    const float* pri_b1 = (const float*)d_in[12];
    const float* pri_W2 = (const float*)d_in[13];
    const float* pri_b2 = (const float*)d_in[14];
    const float* prim_W = (const float*)d_in[15];
    const float* prim_b = (const float*)d_in[16];
    const float* pris_W = (const float*)d_in[17];
    const float* pris_b = (const float*)d_in[18];
    const float* dec_W1 = (const float*)d_in[19];
    const float* dec_b1 = (const float*)d_in[20];
    const float* dec_W2 = (const float*)d_in[21];
    const float* dec_b2 = (const float*)d_in[22];
    const float* decm_W = (const float*)d_in[23];
    const float* decm_b = (const float*)d_in[24];
    const float* decs_W = (const float*)d_in[25];
    const float* decs_b = (const float*)d_in[26];
    const float* gru_Wih = (const float*)d_in[27];
    const float* gru_bih = (const float*)d_in[28];
    const float* gru_Whh = (const float*)d_in[29];
    const float* gru_bhh = (const float*)d_in[30];

    // workspace layout (~46 MB), all activation panels column-major [C][NB] per agent
    double* accd = (double*)d_ws;
    float* base = (float*)((char*)d_ws + 256);
    float* h_ring = base;                              // HR * NA * SA
    float* z_ring = h_ring + (size_t)HR * NA * SA;     // TS * NA * ZA
    float* ench1 = z_ring + (size_t)TS * NA * ZA;
    float* prih1 = ench1 + NA * SA;
    float* ench2 = prih1 + NA * SA;
    float* prih2 = ench2 + NA * SA;
    float* ghB = prih2 + NA * SA;                      // NA * GA
    float* dech1s = ghB + NA * GA;                     // TS * NA * SA
    float* dech2s = dech1s + (size_t)TS * NA * SA;     // TS * NA * SA
    float* out = (float*)d_out;

    k_init<<<320, 256, 0, stream>>>(h_ring, accd);  // h slot 0 = h_0 = zeros
    for (int t = 0; t < NSTEP; ++t) {
        float* h_t = h_ring + (size_t)(t % HR) * NA * SA;
        float* h_nx = h_ring + (size_t)((t + 1) % HR) * NA * SA;
        float* z_t = z_ring + (size_t)(t % TS) * NA * ZA;
        kS1<<<800, 256, 0, stream>>>(h_t, enc_W1, enc_b1, pri_W1, pri_b1, gru_Whh, gru_bhh, data,
                                     macro, ench1, prih1, ghB, t);
        kS2<<<320, 256, 0, stream>>>(ench1, prih1, enc_W2, enc_b2, pri_W2, pri_b2, ench2, prih2);
        kS3<<<80, 256, 0, stream>>>(ench2, prih2, encm_W, encm_b, encs_W, encs_b, prim_W, prim_b,
                                    pris_W, pris_b, eps, z_t, accd, t);
        kS4<<<160, 256, 0, stream>>>(z_t, data, gru_Wih, gru_bih, ghB, h_t, h_nx, t);
        if ((t % TS) == TS - 1) {
            int t0 = t - TS + 1;
            kDec1<<<TS * 160, 256, 0, stream>>>(data, macro, z_ring, h_ring, dec_W1, dec_b1,
                                                dech1s, t0);
            kDec2<<<TS * 160, 256, 0, stream>>>(dech1s, dec_W2, dec_b2, dech2s);
            kEpi<<<TS * 320, 256, 0, stream>>>(dech2s, decm_W, decm_b, decs_W, decs_b, data, accd,
                                               t0);
        }
    }
    k_final<<<1, 64, 0, stream>>>(accd, out);
}